// Round 6
// baseline (1026.654 us; speedup 1.0000x reference)
//
#include <hip/hip_runtime.h>
#include <stdint.h>

typedef unsigned short u16;
typedef short bf16x8 __attribute__((ext_vector_type(8)));
typedef float f32x4 __attribute__((ext_vector_type(4)));

#define NTOK 4096
#define CDIM 512
#define NHEAD 8
#define LAYERS 8
#define MLPD 2048
#define QKVD 1536

__device__ __forceinline__ u16 f2bf(float f){
  union { float f; unsigned u; } c; c.f = f;
  return (u16)((c.u + 0x7FFFu + ((c.u >> 16) & 1u)) >> 16);
}

__device__ __forceinline__ unsigned pack2(float a, float b){
  return (unsigned)f2bf(a) | ((unsigned)f2bf(b) << 16);
}

__device__ __forceinline__ void llds16(const void* g, void* l){
  __builtin_amdgcn_global_load_lds((const __attribute__((address_space(1))) void*)g,
                                   (__attribute__((address_space(3))) void*)l, 16, 0, 0);
}

template<int N> __device__ __forceinline__ void wait_vmcnt(){
  if constexpr (N == 0) asm volatile("s_waitcnt vmcnt(0)" ::: "memory");
  else if constexpr (N == 4) asm volatile("s_waitcnt vmcnt(4)" ::: "memory");
  else static_assert(N == 0 || N == 4, "unsupported vmcnt");
}

// ---------------- weight transpose+convert: W[K][N] fp32 -> Wt[N][K] bf16 ----------------
__global__ void kt_transpose(const float* __restrict__ W, u16* __restrict__ Wt, int K, int N){
  __shared__ float tile[32][33];
  int l = blockIdx.z;
  W  += (size_t)l * K * N;
  Wt += (size_t)l * K * N;
  int k0 = blockIdx.y * 32, n0 = blockIdx.x * 32;
  int t = threadIdx.x;
  int r = t >> 3, c4 = (t & 7) << 2;
  float4 v = *(const float4*)&W[(size_t)(k0 + r) * N + n0 + c4];
  tile[r][c4 + 0] = v.x; tile[r][c4 + 1] = v.y; tile[r][c4 + 2] = v.z; tile[r][c4 + 3] = v.w;
  __syncthreads();
  ushort4 o;
  o.x = f2bf(tile[c4 + 0][r]);
  o.y = f2bf(tile[c4 + 1][r]);
  o.z = f2bf(tile[c4 + 2][r]);
  o.w = f2bf(tile[c4 + 3][r]);
  *(ushort4*)&Wt[(size_t)(n0 + r) * K + k0 + c4] = o;
}

// ---------------- embed: h = feats@w_in + b_in + pos-emb ----------------
__global__ void kt_embed(const float* __restrict__ feats, const int* __restrict__ coords,
                         const float* __restrict__ ex, const float* __restrict__ ey,
                         const float* __restrict__ ez, const float* __restrict__ w_in,
                         const float* __restrict__ b_in, float* __restrict__ h){
  __shared__ float fs[8];
  __shared__ int cc[3];
  int n = blockIdx.x, t = threadIdx.x;
  if (t < 8) fs[t] = feats[n * 8 + t];
  if (t == 8) { cc[0] = coords[n*4+1]; cc[1] = coords[n*4+2]; cc[2] = coords[n*4+3]; }
  __syncthreads();
  for (int c = t; c < CDIM; c += 256){
    float acc = b_in[c];
    #pragma unroll
    for (int i = 0; i < 8; i++) acc += fs[i] * w_in[i * CDIM + c];
    float pe;
    if (c < 170)      pe = ex[cc[0] * 170 + c];
    else if (c < 340) pe = ey[cc[1] * 170 + (c - 170)];
    else              pe = ez[cc[2] * 172 + (c - 340)];
    h[(size_t)n * CDIM + c] = acc + pe;
  }
}

// ---------------- LayerNorm: fp32 h -> bf16 out ----------------
__global__ void kt_ln(const float* __restrict__ h, const float* __restrict__ g,
                      const float* __restrict__ b, u16* __restrict__ out, float eps){
  int wave = threadIdx.x >> 6, lane = threadIdx.x & 63;
  int row = blockIdx.x * 4 + wave;
  const float* hr = h + (size_t)row * CDIM + lane * 8;
  float4 v0 = *(const float4*)hr, v1 = *(const float4*)(hr + 4);
  float x[8] = {v0.x, v0.y, v0.z, v0.w, v1.x, v1.y, v1.z, v1.w};
  float s = 0.f, q = 0.f;
  #pragma unroll
  for (int i = 0; i < 8; i++){ s += x[i]; q += x[i] * x[i]; }
  #pragma unroll
  for (int off = 32; off; off >>= 1){ s += __shfl_xor(s, off); q += __shfl_xor(q, off); }
  float mean = s * (1.0f / CDIM);
  float var  = q * (1.0f / CDIM) - mean * mean;
  float rr = rsqrtf(var + eps);
  int cb = lane * 8;
  u16 u[8];
  #pragma unroll
  for (int i = 0; i < 8; i++)
    u[i] = f2bf((x[i] - mean) * rr * g[cb + i] + b[cb + i]);
  uint4 pk;
  pk.x = (unsigned)u[0] | ((unsigned)u[1] << 16);
  pk.y = (unsigned)u[2] | ((unsigned)u[3] << 16);
  pk.z = (unsigned)u[4] | ((unsigned)u[5] << 16);
  pk.w = (unsigned)u[6] | ((unsigned)u[7] << 16);
  *(uint4*)&out[(size_t)row * CDIM + cb] = pk;
}

// ---------------- bf16 GEMM: C[M=4096][N] = A[M][K] @ Wt[N][K]^T + bias ----------------
// 2-buffer, one __syncthreads per K-step (stage t+1, compute t, sync).
// 4 waves; wave tile (BM/2)x(BN/2). 128x128 -> 64x64 wave tile (16 MFMA : 8 ds_read).
// MODE 0: qkv (Q/K -> outb bf16, V -> vT transposed bf16)
// MODE 1: hres += acc + bias  (fp32 residual)
// MODE 2: outb = bf16(gelu(acc + bias))
template<int BM, int BN, int MODE>
__global__ __launch_bounds__(256) void kt_gemm(
    const u16* __restrict__ A, const u16* __restrict__ Wt, const float* __restrict__ bias,
    u16* __restrict__ outb, float* __restrict__ hres, u16* __restrict__ vT, int N, int K)
{
  constexpr int MF = BM / 32;
  constexpr int NF = BN / 32;
  __shared__ __align__(16) u16 As[2][BM * 64];
  __shared__ __align__(16) u16 Bs[2][BN * 64];
  int tid = threadIdx.x, wave = tid >> 6, lane = tid & 63;
  int m0 = blockIdx.y * BM, n0 = blockIdx.x * BN;
  int wm = wave >> 1, wn = wave & 1;
  f32x4 acc[MF][NF];
  const f32x4 fzero = {0.f, 0.f, 0.f, 0.f};
  #pragma unroll
  for (int m = 0; m < MF; m++)
    #pragma unroll
    for (int n = 0; n < NF; n++) acc[m][n] = fzero;

  int srow = lane >> 3;
  int sblk = (lane & 7) ^ srow;
  const u16* gA = A  + (size_t)(m0 + wave * 8 + srow) * K + sblk * 8;
  const u16* gB = Wt + (size_t)(n0 + wave * 8 + srow) * K + sblk * 8;

  auto stage = [&](int buf, int kt){
    #pragma unroll
    for (int j = 0; j < MF; j++)
      llds16(gA + (size_t)(j * 32) * K + kt, &As[buf][(j * 32 + wave * 8) * 64]);
    #pragma unroll
    for (int j = 0; j < NF; j++)
      llds16(gB + (size_t)(j * 32) * K + kt, &Bs[buf][(j * 32 + wave * 8) * 64]);
  };

  int nk = K >> 6;
  stage(0, 0);
  __syncthreads();
  int rl = lane & 15, hg = lane >> 4;
  for (int t = 0; t < nk; ++t){
    int cur = t & 1;
    if (t + 1 < nk) stage(cur ^ 1, (t + 1) << 6);
    #pragma unroll
    for (int kk = 0; kk < 2; kk++){
      bf16x8 af[MF], bfr[NF];
      int bl = (kk << 2) + hg;
      #pragma unroll
      for (int m = 0; m < MF; m++){
        int row = wm * (BM / 2) + m * 16 + rl;
        af[m] = *(const bf16x8*)&As[cur][row * 64 + ((bl ^ (row & 7)) << 3)];
      }
      #pragma unroll
      for (int n = 0; n < NF; n++){
        int row = wn * (BN / 2) + n * 16 + rl;
        bfr[n] = *(const bf16x8*)&Bs[cur][row * 64 + ((bl ^ (row & 7)) << 3)];
      }
      #pragma unroll
      for (int m = 0; m < MF; m++)
        #pragma unroll
        for (int n = 0; n < NF; n++)
          acc[m][n] = __builtin_amdgcn_mfma_f32_16x16x32_bf16(af[m], bfr[n], acc[m][n], 0, 0, 0);
    }
    __syncthreads();
  }

  int cl = lane & 15, rg = lane >> 4;
  #pragma unroll
  for (int m = 0; m < MF; m++){
    int row0 = m0 + wm * (BM / 2) + m * 16 + rg * 4;
    #pragma unroll
    for (int n = 0; n < NF; n++){
      int col = n0 + wn * (BN / 2) + n * 16 + cl;
      float bb = bias[col];
      if (MODE == 1){
        #pragma unroll
        for (int r = 0; r < 4; r++){
          size_t idx = (size_t)(row0 + r) * N + col;
          hres[idx] += acc[m][n][r] + bb;
        }
      } else if (MODE == 2){
        #pragma unroll
        for (int r = 0; r < 4; r++){
          float x = acc[m][n][r] + bb;
          float t = 0.7978845608028654f * (x + 0.044715f * x * x * x);
          float sg = 1.0f / (1.0f + __expf(-2.0f * t));   // 0.5*(1+tanh(t)) == sigmoid(2t)
          outb[(size_t)(row0 + r) * N + col] = f2bf(x * sg);
        }
      } else {
        if (col < 1024){
          #pragma unroll
          for (int r = 0; r < 4; r++)
            outb[(size_t)(row0 + r) * N + col] = f2bf(acc[m][n][r] + bb);
        } else {
          int dh = col - 1024;
          int win = row0 >> 9, tin = row0 & 511;
          ushort4 p;
          p.x = f2bf(acc[m][n][0] + bb);
          p.y = f2bf(acc[m][n][1] + bb);
          p.z = f2bf(acc[m][n][2] + bb);
          p.w = f2bf(acc[m][n][3] + bb);
          *(ushort4*)&vT[(size_t)(win * 512 + dh) * 512 + tin] = p;
        }
      }
    }
  }
}

// ---------------- windowed flash attention: LDS-staged K/V (3-buf, counted vmcnt) -------
// 1024 blocks x 2 waves (128 thr); block = 32 q-rows of one (win, head).
__global__ __launch_bounds__(128) void kt_attn(const u16* __restrict__ qkv,
                                               const u16* __restrict__ vT,
                                               u16* __restrict__ o){
  __shared__ __align__(16) u16 Ks[3][32 * 64];
  __shared__ __align__(16) u16 Vs[3][64 * 32];
  int tid = threadIdx.x, wave = tid >> 6, lane = tid & 63;
  int bx = blockIdx.x;
  int win = bx >> 7, head = (bx >> 4) & 7, q16 = bx & 15;
  int rl = lane & 15, hg = lane >> 4;
  int qbase = win * 512 + q16 * 32 + wave * 16;
  const u16* qptr  = qkv + (size_t)(qbase + rl) * QKVD + head * 64;
  const u16* kbase = qkv + (size_t)(win * 512) * QKVD + 512 + head * 64;
  const u16* vbase = vT + (size_t)(win * 512 + head * 64) * 512;

  // staging sources (pre-swizzled so linear llds16 dest + swizzled read match)
  int krow = tid >> 3;                                   // 0..15
  const u16* gK = kbase + (size_t)krow * QKVD + (((tid & 7) ^ (krow & 7)) << 3);
  int vrow = tid >> 2;                                   // 0..31
  const u16* gV = vbase + (size_t)vrow * 512 + (((tid & 3) ^ (vrow & 3)) << 3);

  auto stage = [&](int buf, int kt){
    llds16(gK + (size_t)kt * QKVD,        &Ks[buf][tid * 8]);
    llds16(gK + (size_t)(kt + 16) * QKVD, &Ks[buf][1024 + tid * 8]);
    llds16(gV + kt,                       &Vs[buf][tid * 8]);
    llds16(gV + (size_t)32 * 512 + kt,    &Vs[buf][1024 + tid * 8]);
  };

  bf16x8 qf0 = *(const bf16x8*)(qptr + hg * 8);
  bf16x8 qf1 = *(const bf16x8*)(qptr + 32 + hg * 8);

  const f32x4 fzero = {0.f, 0.f, 0.f, 0.f};
  f32x4 Oa[4] = {fzero, fzero, fzero, fzero};
  float mrun = -1e30f, lrun = 0.f;

  stage(0, 0);
  stage(1, 32);
  for (int t = 0; t < 16; ++t){
    int cur = t % 3;
    if (t + 1 < 16) wait_vmcnt<4>(); else wait_vmcnt<0>();
    __builtin_amdgcn_s_barrier();
    asm volatile("" ::: "memory");
    if (t + 2 < 16) stage((t + 2) % 3, (t + 2) * 32);

    bf16x8 kf[2][2];
    #pragma unroll
    for (int c = 0; c < 2; c++)
      #pragma unroll
      for (int dk = 0; dk < 2; dk++){
        int row = c * 16 + rl;
        kf[c][dk] = *(const bf16x8*)&Ks[cur][row * 64 + ((((dk << 2) + hg) ^ (rl & 7)) << 3)];
      }
    bf16x8 vf[4];
    #pragma unroll
    for (int d = 0; d < 4; d++){
      int row = d * 16 + rl;
      vf[d] = *(const bf16x8*)&Vs[cur][row * 32 + ((hg ^ (rl & 3)) << 3)];
    }

    f32x4 s0 = fzero, s1 = fzero;
    s0 = __builtin_amdgcn_mfma_f32_16x16x32_bf16(kf[0][0], qf0, s0, 0, 0, 0);
    s0 = __builtin_amdgcn_mfma_f32_16x16x32_bf16(kf[0][1], qf1, s0, 0, 0, 0);
    s1 = __builtin_amdgcn_mfma_f32_16x16x32_bf16(kf[1][0], qf0, s1, 0, 0, 0);
    s1 = __builtin_amdgcn_mfma_f32_16x16x32_bf16(kf[1][1], qf1, s1, 0, 0, 0);
    float v[8];
    #pragma unroll
    for (int r = 0; r < 4; r++){ v[r] = s0[r] * 0.125f; v[4 + r] = s1[r] * 0.125f; }
    float tmax = v[0];
    #pragma unroll
    for (int i = 1; i < 8; i++) tmax = fmaxf(tmax, v[i]);
    tmax = fmaxf(tmax, __shfl_xor(tmax, 16));
    tmax = fmaxf(tmax, __shfl_xor(tmax, 32));
    float mnew = fmaxf(mrun, tmax);
    float corr = __expf(mrun - mnew);
    mrun = mnew;
    float p[8], ps = 0.f;
    #pragma unroll
    for (int i = 0; i < 8; i++){ p[i] = __expf(v[i] - mnew); ps += p[i]; }
    ps += __shfl_xor(ps, 16);
    ps += __shfl_xor(ps, 32);
    lrun = lrun * corr + ps;
    float c0 = __shfl(corr, (hg << 2) + 0);
    float c1 = __shfl(corr, (hg << 2) + 1);
    float c2 = __shfl(corr, (hg << 2) + 2);
    float c3 = __shfl(corr, (hg << 2) + 3);
    #pragma unroll
    for (int d = 0; d < 4; d++){
      Oa[d][0] *= c0; Oa[d][1] *= c1; Oa[d][2] *= c2; Oa[d][3] *= c3;
    }
    unsigned pk00 = pack2(p[0], p[1]);
    unsigned pk01 = pack2(p[2], p[3]);
    unsigned pk10 = pack2(p[4], p[5]);
    unsigned pk11 = pack2(p[6], p[7]);
    int idx0 = rl | ((( hg << 1)      & 3) << 4);
    int idx1 = rl | ((((hg << 1) + 1) & 3) << 4);
    bool hiC = hg >= 2;
    unsigned W0a = __shfl(pk00, idx0), W0b = __shfl(pk10, idx0);
    unsigned W1a = __shfl(pk01, idx0), W1b = __shfl(pk11, idx0);
    unsigned W2a = __shfl(pk00, idx1), W2b = __shfl(pk10, idx1);
    unsigned W3a = __shfl(pk01, idx1), W3b = __shfl(pk11, idx1);
    uint4 W;
    W.x = hiC ? W0b : W0a;
    W.y = hiC ? W1b : W1a;
    W.z = hiC ? W2b : W2a;
    W.w = hiC ? W3b : W3a;
    bf16x8 pf;
    __builtin_memcpy(&pf, &W, 16);
    #pragma unroll
    for (int d = 0; d < 4; d++)
      Oa[d] = __builtin_amdgcn_mfma_f32_16x16x32_bf16(pf, vf[d], Oa[d], 0, 0, 0);
  }

  float l0 = __shfl(lrun, (hg << 2) + 0);
  float l1 = __shfl(lrun, (hg << 2) + 1);
  float l2 = __shfl(lrun, (hg << 2) + 2);
  float l3 = __shfl(lrun, (hg << 2) + 3);
  float li[4] = {1.f / l0, 1.f / l1, 1.f / l2, 1.f / l3};
  #pragma unroll
  for (int d = 0; d < 4; d++)
    #pragma unroll
    for (int r = 0; r < 4; r++){
      int row = qbase + (hg << 2) + r;
      o[(size_t)row * CDIM + head * 64 + d * 16 + rl] = f2bf(Oa[d][r] * li[r]);
    }
}

// ---------------- final LN + head + gaussian post-process ----------------
__global__ void kt_final(const float* __restrict__ h, const float* __restrict__ w_out,
                         const float* __restrict__ b_out, const int* __restrict__ coords,
                         const float* __restrict__ offp, float* __restrict__ out){
  __shared__ float lnv[CDIM];
  __shared__ float ov[56];
  int n = blockIdx.x, lane = threadIdx.x;   // 64 threads
  const float* hr = h + (size_t)n * CDIM + lane * 8;
  float4 v0 = *(const float4*)hr, v1 = *(const float4*)(hr + 4);
  float x[8] = {v0.x, v0.y, v0.z, v0.w, v1.x, v1.y, v1.z, v1.w};
  float s = 0.f, q = 0.f;
  #pragma unroll
  for (int i = 0; i < 8; i++){ s += x[i]; q += x[i] * x[i]; }
  #pragma unroll
  for (int off = 32; off; off >>= 1){ s += __shfl_xor(s, off); q += __shfl_xor(q, off); }
  float mean = s * (1.0f / CDIM);
  float var  = q * (1.0f / CDIM) - mean * mean;
  float rr = rsqrtf(var + 1e-5f);
  #pragma unroll
  for (int i = 0; i < 8; i++) lnv[lane * 8 + i] = (x[i] - mean) * rr;
  __syncthreads();
  if (lane < 56){
    float a = b_out[lane];
    for (int k = 0; k < CDIM; k++) a += lnv[k] * w_out[k * 56 + lane];
    ov[lane] = a;
  }
  __syncthreads();
  if (lane < 12){
    int g = lane / 3, d = lane - g * 3;
    float base = ((float)coords[n * 4 + 1 + d] + 0.5f) * (1.0f / 16.0f);
    float t = tanhf(ov[lane] + offp[lane]);
    out[(size_t)n * 12 + lane] = base + t * 4.8828125e-4f;
    out[49152  + (size_t)n * 12 + lane] = ov[12 + lane];
    out[98304  + (size_t)n * 12 + lane] = ov[24 + lane];
  }
  if (lane < 16) out[147456 + (size_t)n * 16 + lane] = ov[36 + lane];
  if (lane < 4)  out[212992 + (size_t)n * 4  + lane] = ov[52 + lane];
}

extern "C" void kernel_launch(void* const* d_in, const int* in_sizes, int n_in,
                              void* d_out, int out_size, void* d_ws, size_t ws_size,
                              hipStream_t stream) {
  const float* feats = (const float*)d_in[0];
  const int*   coords = (const int*)d_in[1];
  const float* emb_x = (const float*)d_in[2];
  const float* emb_y = (const float*)d_in[3];
  const float* emb_z = (const float*)d_in[4];
  const float* w_in  = (const float*)d_in[5];
  const float* b_in  = (const float*)d_in[6];
  const float* ln1_g = (const float*)d_in[7];
  const float* ln1_b = (const float*)d_in[8];
  const float* w_qkv = (const float*)d_in[9];
  const float* b_qkv = (const float*)d_in[10];
  const float* w_o   = (const float*)d_in[11];
  const float* b_o   = (const float*)d_in[12];
  const float* ln2_g = (const float*)d_in[13];
  const float* ln2_b = (const float*)d_in[14];
  const float* w_m1  = (const float*)d_in[15];
  const float* b_m1  = (const float*)d_in[16];
  const float* w_m2  = (const float*)d_in[17];
  const float* b_m2  = (const float*)d_in[18];
  const float* w_out = (const float*)d_in[19];
  const float* b_out = (const float*)d_in[20];
  const float* offp  = (const float*)d_in[21];

  char* ws = (char*)d_ws;
  auto carve = [&](size_t bytes){ char* p = ws; ws += (bytes + 255) & ~(size_t)255; return p; };
  float* h   = (float*)carve((size_t)NTOK * CDIM * 4);
  u16* a     = (u16*)carve((size_t)NTOK * CDIM * 2);
  u16* qkvb  = (u16*)carve((size_t)NTOK * QKVD * 2);
  u16* vT    = (u16*)carve((size_t)NTOK * CDIM * 2);
  u16* ob    = (u16*)carve((size_t)NTOK * CDIM * 2);
  u16* ub    = (u16*)carve((size_t)NTOK * MLPD * 2);
  u16* wqkvT = (u16*)carve((size_t)LAYERS * QKVD * CDIM * 2);
  u16* woT   = (u16*)carve((size_t)LAYERS * CDIM * CDIM * 2);
  u16* wm1T  = (u16*)carve((size_t)LAYERS * MLPD * CDIM * 2);
  u16* wm2T  = (u16*)carve((size_t)LAYERS * CDIM * MLPD * 2);

  kt_transpose<<<dim3(QKVD/32, CDIM/32, LAYERS), 256, 0, stream>>>(w_qkv, wqkvT, CDIM, QKVD);
  kt_transpose<<<dim3(CDIM/32, CDIM/32, LAYERS), 256, 0, stream>>>(w_o,   woT,   CDIM, CDIM);
  kt_transpose<<<dim3(MLPD/32, CDIM/32, LAYERS), 256, 0, stream>>>(w_m1,  wm1T,  CDIM, MLPD);
  kt_transpose<<<dim3(CDIM/32, MLPD/32, LAYERS), 256, 0, stream>>>(w_m2,  wm2T,  MLPD, CDIM);
  kt_embed<<<NTOK, 256, 0, stream>>>(feats, coords, emb_x, emb_y, emb_z, w_in, b_in, h);

  for (int l = 0; l < LAYERS; ++l){
    kt_ln<<<NTOK/4, 256, 0, stream>>>(h, ln1_g + l*CDIM, ln1_b + l*CDIM, a, 1e-6f);
    kt_gemm<128,128,0><<<dim3(QKVD/128, NTOK/128), 256, 0, stream>>>(
        a, wqkvT + (size_t)l*QKVD*CDIM, b_qkv + l*QKVD, qkvb, nullptr, vT, QKVD, CDIM);
    kt_attn<<<1024, 128, 0, stream>>>(qkvb, vT, ob);
    kt_gemm<128,64,1><<<dim3(CDIM/64, NTOK/128), 256, 0, stream>>>(
        ob, woT + (size_t)l*CDIM*CDIM, b_o + l*CDIM, nullptr, h, nullptr, CDIM, CDIM);
    kt_ln<<<NTOK/4, 256, 0, stream>>>(h, ln2_g + l*CDIM, ln2_b + l*CDIM, a, 1e-6f);
    kt_gemm<128,128,2><<<dim3(MLPD/128, NTOK/128), 256, 0, stream>>>(
        a, wm1T + (size_t)l*MLPD*CDIM, b_m1 + l*MLPD, ub, nullptr, nullptr, MLPD, CDIM);
    kt_gemm<128,64,1><<<dim3(CDIM/64, NTOK/128), 256, 0, stream>>>(
        ub, wm2T + (size_t)l*CDIM*MLPD, b_m2 + l*CDIM, nullptr, h, nullptr, CDIM, MLPD);
  }
  kt_final<<<NTOK, 64, 0, stream>>>(h, w_out, b_out, coords, offp, (float*)d_out);
}

// Round 7
// 855.205 us; speedup vs baseline: 1.2005x; 1.2005x over previous
//
#include <hip/hip_runtime.h>
#include <stdint.h>

typedef unsigned short u16;
typedef short bf16x8 __attribute__((ext_vector_type(8)));
typedef float f32x4 __attribute__((ext_vector_type(4)));

#define NTOK 4096
#define CDIM 512
#define NHEAD 8
#define LAYERS 8
#define MLPD 2048
#define QKVD 1536

__device__ __forceinline__ u16 f2bf(float f){
  union { float f; unsigned u; } c; c.f = f;
  return (u16)((c.u + 0x7FFFu + ((c.u >> 16) & 1u)) >> 16);
}

__device__ __forceinline__ unsigned pack2(float a, float b){
  return (unsigned)f2bf(a) | ((unsigned)f2bf(b) << 16);
}

__device__ __forceinline__ void llds16(const void* g, void* l){
  __builtin_amdgcn_global_load_lds((const __attribute__((address_space(1))) void*)g,
                                   (__attribute__((address_space(3))) void*)l, 16, 0, 0);
}

template<int N> __device__ __forceinline__ void wait_vmcnt(){
  if constexpr (N == 0) asm volatile("s_waitcnt vmcnt(0)" ::: "memory");
  else if constexpr (N == 2) asm volatile("s_waitcnt vmcnt(2)" ::: "memory");
  else if constexpr (N == 4) asm volatile("s_waitcnt vmcnt(4)" ::: "memory");
  else static_assert(N == 0 || N == 2 || N == 4, "unsupported vmcnt");
}

// ---------------- weight transpose+convert: W[K][N] fp32 -> Wt[N][K] bf16 ----------------
__global__ void kt_transpose(const float* __restrict__ W, u16* __restrict__ Wt, int K, int N){
  __shared__ float tile[32][33];
  int l = blockIdx.z;
  W  += (size_t)l * K * N;
  Wt += (size_t)l * K * N;
  int k0 = blockIdx.y * 32, n0 = blockIdx.x * 32;
  int t = threadIdx.x;
  int r = t >> 3, c4 = (t & 7) << 2;
  float4 v = *(const float4*)&W[(size_t)(k0 + r) * N + n0 + c4];
  tile[r][c4 + 0] = v.x; tile[r][c4 + 1] = v.y; tile[r][c4 + 2] = v.z; tile[r][c4 + 3] = v.w;
  __syncthreads();
  ushort4 o;
  o.x = f2bf(tile[c4 + 0][r]);
  o.y = f2bf(tile[c4 + 1][r]);
  o.z = f2bf(tile[c4 + 2][r]);
  o.w = f2bf(tile[c4 + 3][r]);
  *(ushort4*)&Wt[(size_t)(n0 + r) * K + k0 + c4] = o;
}

// ---------------- embed: h = feats@w_in + b_in + pos-emb ----------------
__global__ void kt_embed(const float* __restrict__ feats, const int* __restrict__ coords,
                         const float* __restrict__ ex, const float* __restrict__ ey,
                         const float* __restrict__ ez, const float* __restrict__ w_in,
                         const float* __restrict__ b_in, float* __restrict__ h){
  __shared__ float fs[8];
  __shared__ int cc[3];
  int n = blockIdx.x, t = threadIdx.x;
  if (t < 8) fs[t] = feats[n * 8 + t];
  if (t == 8) { cc[0] = coords[n*4+1]; cc[1] = coords[n*4+2]; cc[2] = coords[n*4+3]; }
  __syncthreads();
  for (int c = t; c < CDIM; c += 256){
    float acc = b_in[c];
    #pragma unroll
    for (int i = 0; i < 8; i++) acc += fs[i] * w_in[i * CDIM + c];
    float pe;
    if (c < 170)      pe = ex[cc[0] * 170 + c];
    else if (c < 340) pe = ey[cc[1] * 170 + (c - 170)];
    else              pe = ez[cc[2] * 172 + (c - 340)];
    h[(size_t)n * CDIM + c] = acc + pe;
  }
}

// ---------------- LayerNorm: fp32 h -> bf16 out ----------------
__global__ void kt_ln(const float* __restrict__ h, const float* __restrict__ g,
                      const float* __restrict__ b, u16* __restrict__ out, float eps){
  int wave = threadIdx.x >> 6, lane = threadIdx.x & 63;
  int row = blockIdx.x * 4 + wave;
  const float* hr = h + (size_t)row * CDIM + lane * 8;
  float4 v0 = *(const float4*)hr, v1 = *(const float4*)(hr + 4);
  float x[8] = {v0.x, v0.y, v0.z, v0.w, v1.x, v1.y, v1.z, v1.w};
  float s = 0.f, q = 0.f;
  #pragma unroll
  for (int i = 0; i < 8; i++){ s += x[i]; q += x[i] * x[i]; }
  #pragma unroll
  for (int off = 32; off; off >>= 1){ s += __shfl_xor(s, off); q += __shfl_xor(q, off); }
  float mean = s * (1.0f / CDIM);
  float var  = q * (1.0f / CDIM) - mean * mean;
  float rr = rsqrtf(var + eps);
  int cb = lane * 8;
  u16 u[8];
  #pragma unroll
  for (int i = 0; i < 8; i++)
    u[i] = f2bf((x[i] - mean) * rr * g[cb + i] + b[cb + i]);
  uint4 pk;
  pk.x = (unsigned)u[0] | ((unsigned)u[1] << 16);
  pk.y = (unsigned)u[2] | ((unsigned)u[3] << 16);
  pk.z = (unsigned)u[4] | ((unsigned)u[5] << 16);
  pk.w = (unsigned)u[6] | ((unsigned)u[7] << 16);
  *(uint4*)&out[(size_t)row * CDIM + cb] = pk;
}

// ---------------- bf16 GEMM: C[M=4096][N] = A[M][K] @ Wt[N][K]^T + bias ----------------
// 2-buffer, one __syncthreads per K-step. 4 waves; wave tile (BM/2)x(BN/2).
// XCD-chunked 1D grid swizzle: blocks resident on one XCD share Mx A-panels +
// Nt B-panels (fits 4MB per-XCD L2), fixing the cross-XCD A-panel re-fetch.
// MODE 0: qkv (Q/K -> outb bf16, V -> vT transposed bf16)
// MODE 1: hres += acc + bias  (fp32 residual)
// MODE 2: outb = bf16(gelu(acc + bias))
template<int BM, int BN, int MODE>
__global__ __launch_bounds__(256) void kt_gemm(
    const u16* __restrict__ A, const u16* __restrict__ Wt, const float* __restrict__ bias,
    u16* __restrict__ outb, float* __restrict__ hres, u16* __restrict__ vT, int N, int K)
{
  constexpr int MF = BM / 32;
  constexpr int NF = BN / 32;
  constexpr int Mt = NTOK / BM;
  constexpr int Mx = Mt / 8;
  __shared__ __align__(16) u16 As[2][BM * 64];
  __shared__ __align__(16) u16 Bs[2][BN * 64];
  int tid = threadIdx.x, wave = tid >> 6, lane = tid & 63;

  int Nt = N / BN;
  int bid = blockIdx.x;
  int xcd = bid & 7, slot = bid >> 3;
  int miL = slot / Nt;
  int ni = slot - miL * Nt;
  int m0 = (xcd * Mx + miL) * BM, n0 = ni * BN;

  int wm = wave >> 1, wn = wave & 1;
  f32x4 acc[MF][NF];
  const f32x4 fzero = {0.f, 0.f, 0.f, 0.f};
  #pragma unroll
  for (int m = 0; m < MF; m++)
    #pragma unroll
    for (int n = 0; n < NF; n++) acc[m][n] = fzero;

  int srow = lane >> 3;
  int sblk = (lane & 7) ^ srow;
  const u16* gA = A  + (size_t)(m0 + wave * 8 + srow) * K + sblk * 8;
  const u16* gB = Wt + (size_t)(n0 + wave * 8 + srow) * K + sblk * 8;

  auto stage = [&](int buf, int kt){
    #pragma unroll
    for (int j = 0; j < MF; j++)
      llds16(gA + (size_t)(j * 32) * K + kt, &As[buf][(j * 32 + wave * 8) * 64]);
    #pragma unroll
    for (int j = 0; j < NF; j++)
      llds16(gB + (size_t)(j * 32) * K + kt, &Bs[buf][(j * 32 + wave * 8) * 64]);
  };

  int nk = K >> 6;
  stage(0, 0);
  __syncthreads();
  int rl = lane & 15, hg = lane >> 4;
  for (int t = 0; t < nk; ++t){
    int cur = t & 1;
    if (t + 1 < nk) stage(cur ^ 1, (t + 1) << 6);
    #pragma unroll
    for (int kk = 0; kk < 2; kk++){
      bf16x8 af[MF], bfr[NF];
      int bl = (kk << 2) + hg;
      #pragma unroll
      for (int m = 0; m < MF; m++){
        int row = wm * (BM / 2) + m * 16 + rl;
        af[m] = *(const bf16x8*)&As[cur][row * 64 + ((bl ^ (row & 7)) << 3)];
      }
      #pragma unroll
      for (int n = 0; n < NF; n++){
        int row = wn * (BN / 2) + n * 16 + rl;
        bfr[n] = *(const bf16x8*)&Bs[cur][row * 64 + ((bl ^ (row & 7)) << 3)];
      }
      #pragma unroll
      for (int m = 0; m < MF; m++)
        #pragma unroll
        for (int n = 0; n < NF; n++)
          acc[m][n] = __builtin_amdgcn_mfma_f32_16x16x32_bf16(af[m], bfr[n], acc[m][n], 0, 0, 0);
    }
    __syncthreads();
  }

  int cl = lane & 15, rg = lane >> 4;
  #pragma unroll
  for (int m = 0; m < MF; m++){
    int row0 = m0 + wm * (BM / 2) + m * 16 + rg * 4;
    #pragma unroll
    for (int n = 0; n < NF; n++){
      int col = n0 + wn * (BN / 2) + n * 16 + cl;
      float bb = bias[col];
      if (MODE == 1){
        #pragma unroll
        for (int r = 0; r < 4; r++){
          size_t idx = (size_t)(row0 + r) * N + col;
          hres[idx] += acc[m][n][r] + bb;
        }
      } else if (MODE == 2){
        #pragma unroll
        for (int r = 0; r < 4; r++){
          float x = acc[m][n][r] + bb;
          float t = 0.7978845608028654f * (x + 0.044715f * x * x * x);
          float sg = 1.0f / (1.0f + __expf(-2.0f * t));   // 0.5*(1+tanh(t)) == sigmoid(2t)
          outb[(size_t)(row0 + r) * N + col] = f2bf(x * sg);
        }
      } else {
        if (col < 1024){
          #pragma unroll
          for (int r = 0; r < 4; r++)
            outb[(size_t)(row0 + r) * N + col] = f2bf(acc[m][n][r] + bb);
        } else {
          int dh = col - 1024;
          int win = row0 >> 9, tin = row0 & 511;
          ushort4 p;
          p.x = f2bf(acc[m][n][0] + bb);
          p.y = f2bf(acc[m][n][1] + bb);
          p.z = f2bf(acc[m][n][2] + bb);
          p.w = f2bf(acc[m][n][3] + bb);
          *(ushort4*)&vT[(size_t)(win * 512 + dh) * 512 + tin] = p;
        }
      }
    }
  }
}

// ---------------- windowed flash attention: LDS-staged K/V (3-buf, counted vmcnt) -------
// 512 blocks x 4 waves; block = 64 q-rows of one (win, head); K/V tiles shared via LDS.
__global__ __launch_bounds__(256) void kt_attn(const u16* __restrict__ qkv,
                                               const u16* __restrict__ vT,
                                               u16* __restrict__ o){
  __shared__ __align__(16) u16 Ks[3][32 * 64];
  __shared__ __align__(16) u16 Vs[3][64 * 32];
  int tid = threadIdx.x, wave = tid >> 6, lane = tid & 63;
  int bx = blockIdx.x;
  int win = bx >> 6, head = (bx >> 3) & 7, q8 = bx & 7;
  int rl = lane & 15, hg = lane >> 4;
  int qbase = win * 512 + q8 * 64 + wave * 16;
  const u16* qptr  = qkv + (size_t)(qbase + rl) * QKVD + head * 64;
  const u16* kbase = qkv + (size_t)(win * 512) * QKVD + 512 + head * 64;
  const u16* vbase = vT + (size_t)(win * 512 + head * 64) * 512;

  int krow = tid >> 3;
  const u16* gK = kbase + (size_t)krow * QKVD + (((tid & 7) ^ (krow & 7)) << 3);
  int vrow = tid >> 2;
  const u16* gV = vbase + (size_t)vrow * 512 + (((tid & 3) ^ (vrow & 3)) << 3);

  auto stage = [&](int buf, int kt){
    llds16(gK + (size_t)kt * QKVD, &Ks[buf][tid * 8]);
    llds16(gV + kt, &Vs[buf][tid * 8]);
  };

  bf16x8 qf0 = *(const bf16x8*)(qptr + hg * 8);
  bf16x8 qf1 = *(const bf16x8*)(qptr + 32 + hg * 8);

  const f32x4 fzero = {0.f, 0.f, 0.f, 0.f};
  f32x4 Oa[4] = {fzero, fzero, fzero, fzero};
  float mrun = -1e30f, lrun = 0.f;

  stage(0, 0);
  stage(1, 32);
  for (int t = 0; t < 16; ++t){
    int cur = t % 3;
    if (t + 1 < 16) wait_vmcnt<2>(); else wait_vmcnt<0>();
    __builtin_amdgcn_s_barrier();
    asm volatile("" ::: "memory");
    if (t + 2 < 16) stage((t + 2) % 3, (t + 2) * 32);

    bf16x8 kf[2][2];
    #pragma unroll
    for (int c = 0; c < 2; c++)
      #pragma unroll
      for (int dk = 0; dk < 2; dk++){
        int row = c * 16 + rl;
        kf[c][dk] = *(const bf16x8*)&Ks[cur][row * 64 + ((((dk << 2) + hg) ^ (rl & 7)) << 3)];
      }
    bf16x8 vf[4];
    #pragma unroll
    for (int d = 0; d < 4; d++){
      int row = d * 16 + rl;
      vf[d] = *(const bf16x8*)&Vs[cur][row * 32 + ((hg ^ (rl & 3)) << 3)];
    }

    f32x4 s0 = fzero, s1 = fzero;
    s0 = __builtin_amdgcn_mfma_f32_16x16x32_bf16(kf[0][0], qf0, s0, 0, 0, 0);
    s0 = __builtin_amdgcn_mfma_f32_16x16x32_bf16(kf[0][1], qf1, s0, 0, 0, 0);
    s1 = __builtin_amdgcn_mfma_f32_16x16x32_bf16(kf[1][0], qf0, s1, 0, 0, 0);
    s1 = __builtin_amdgcn_mfma_f32_16x16x32_bf16(kf[1][1], qf1, s1, 0, 0, 0);
    float v[8];
    #pragma unroll
    for (int r = 0; r < 4; r++){ v[r] = s0[r] * 0.125f; v[4 + r] = s1[r] * 0.125f; }
    float tmax = v[0];
    #pragma unroll
    for (int i = 1; i < 8; i++) tmax = fmaxf(tmax, v[i]);
    tmax = fmaxf(tmax, __shfl_xor(tmax, 16));
    tmax = fmaxf(tmax, __shfl_xor(tmax, 32));
    float mnew = fmaxf(mrun, tmax);
    float corr = __expf(mrun - mnew);
    mrun = mnew;
    float p[8], ps = 0.f;
    #pragma unroll
    for (int i = 0; i < 8; i++){ p[i] = __expf(v[i] - mnew); ps += p[i]; }
    ps += __shfl_xor(ps, 16);
    ps += __shfl_xor(ps, 32);
    lrun = lrun * corr + ps;
    float c0 = __shfl(corr, (hg << 2) + 0);
    float c1 = __shfl(corr, (hg << 2) + 1);
    float c2 = __shfl(corr, (hg << 2) + 2);
    float c3 = __shfl(corr, (hg << 2) + 3);
    #pragma unroll
    for (int d = 0; d < 4; d++){
      Oa[d][0] *= c0; Oa[d][1] *= c1; Oa[d][2] *= c2; Oa[d][3] *= c3;
    }
    unsigned pk00 = pack2(p[0], p[1]);
    unsigned pk01 = pack2(p[2], p[3]);
    unsigned pk10 = pack2(p[4], p[5]);
    unsigned pk11 = pack2(p[6], p[7]);
    int idx0 = rl | ((( hg << 1)      & 3) << 4);
    int idx1 = rl | ((((hg << 1) + 1) & 3) << 4);
    bool hiC = hg >= 2;
    unsigned W0a = __shfl(pk00, idx0), W0b = __shfl(pk10, idx0);
    unsigned W1a = __shfl(pk01, idx0), W1b = __shfl(pk11, idx0);
    unsigned W2a = __shfl(pk00, idx1), W2b = __shfl(pk10, idx1);
    unsigned W3a = __shfl(pk01, idx1), W3b = __shfl(pk11, idx1);
    uint4 W;
    W.x = hiC ? W0b : W0a;
    W.y = hiC ? W1b : W1a;
    W.z = hiC ? W2b : W2a;
    W.w = hiC ? W3b : W3a;
    bf16x8 pf;
    __builtin_memcpy(&pf, &W, 16);
    #pragma unroll
    for (int d = 0; d < 4; d++)
      Oa[d] = __builtin_amdgcn_mfma_f32_16x16x32_bf16(pf, vf[d], Oa[d], 0, 0, 0);
  }

  float l0 = __shfl(lrun, (hg << 2) + 0);
  float l1 = __shfl(lrun, (hg << 2) + 1);
  float l2 = __shfl(lrun, (hg << 2) + 2);
  float l3 = __shfl(lrun, (hg << 2) + 3);
  float li[4] = {1.f / l0, 1.f / l1, 1.f / l2, 1.f / l3};
  #pragma unroll
  for (int d = 0; d < 4; d++)
    #pragma unroll
    for (int r = 0; r < 4; r++){
      int row = qbase + (hg << 2) + r;
      o[(size_t)row * CDIM + head * 64 + d * 16 + rl] = f2bf(Oa[d][r] * li[r]);
    }
}

// ---------------- final LN + head + gaussian post-process ----------------
__global__ void kt_final(const float* __restrict__ h, const float* __restrict__ w_out,
                         const float* __restrict__ b_out, const int* __restrict__ coords,
                         const float* __restrict__ offp, float* __restrict__ out){
  __shared__ float lnv[CDIM];
  __shared__ float ov[56];
  int n = blockIdx.x, lane = threadIdx.x;   // 64 threads
  const float* hr = h + (size_t)n * CDIM + lane * 8;
  float4 v0 = *(const float4*)hr, v1 = *(const float4*)(hr + 4);
  float x[8] = {v0.x, v0.y, v0.z, v0.w, v1.x, v1.y, v1.z, v1.w};
  float s = 0.f, q = 0.f;
  #pragma unroll
  for (int i = 0; i < 8; i++){ s += x[i]; q += x[i] * x[i]; }
  #pragma unroll
  for (int off = 32; off; off >>= 1){ s += __shfl_xor(s, off); q += __shfl_xor(q, off); }
  float mean = s * (1.0f / CDIM);
  float var  = q * (1.0f / CDIM) - mean * mean;
  float rr = rsqrtf(var + 1e-5f);
  #pragma unroll
  for (int i = 0; i < 8; i++) lnv[lane * 8 + i] = (x[i] - mean) * rr;
  __syncthreads();
  if (lane < 56){
    float a = b_out[lane];
    for (int k = 0; k < CDIM; k++) a += lnv[k] * w_out[k * 56 + lane];
    ov[lane] = a;
  }
  __syncthreads();
  if (lane < 12){
    int g = lane / 3, d = lane - g * 3;
    float base = ((float)coords[n * 4 + 1 + d] + 0.5f) * (1.0f / 16.0f);
    float t = tanhf(ov[lane] + offp[lane]);
    out[(size_t)n * 12 + lane] = base + t * 4.8828125e-4f;
    out[49152  + (size_t)n * 12 + lane] = ov[12 + lane];
    out[98304  + (size_t)n * 12 + lane] = ov[24 + lane];
  }
  if (lane < 16) out[147456 + (size_t)n * 16 + lane] = ov[36 + lane];
  if (lane < 4)  out[212992 + (size_t)n * 4  + lane] = ov[52 + lane];
}

extern "C" void kernel_launch(void* const* d_in, const int* in_sizes, int n_in,
                              void* d_out, int out_size, void* d_ws, size_t ws_size,
                              hipStream_t stream) {
  const float* feats = (const float*)d_in[0];
  const int*   coords = (const int*)d_in[1];
  const float* emb_x = (const float*)d_in[2];
  const float* emb_y = (const float*)d_in[3];
  const float* emb_z = (const float*)d_in[4];
  const float* w_in  = (const float*)d_in[5];
  const float* b_in  = (const float*)d_in[6];
  const float* ln1_g = (const float*)d_in[7];
  const float* ln1_b = (const float*)d_in[8];
  const float* w_qkv = (const float*)d_in[9];
  const float* b_qkv = (const float*)d_in[10];
  const float* w_o   = (const float*)d_in[11];
  const float* b_o   = (const float*)d_in[12];
  const float* ln2_g = (const float*)d_in[13];
  const float* ln2_b = (const float*)d_in[14];
  const float* w_m1  = (const float*)d_in[15];
  const float* b_m1  = (const float*)d_in[16];
  const float* w_m2  = (const float*)d_in[17];
  const float* b_m2  = (const float*)d_in[18];
  const float* w_out = (const float*)d_in[19];
  const float* b_out = (const float*)d_in[20];
  const float* offp  = (const float*)d_in[21];

  char* ws = (char*)d_ws;
  auto carve = [&](size_t bytes){ char* p = ws; ws += (bytes + 255) & ~(size_t)255; return p; };
  float* h   = (float*)carve((size_t)NTOK * CDIM * 4);
  u16* a     = (u16*)carve((size_t)NTOK * CDIM * 2);
  u16* qkvb  = (u16*)carve((size_t)NTOK * QKVD * 2);
  u16* vT    = (u16*)carve((size_t)NTOK * CDIM * 2);
  u16* ob    = (u16*)carve((size_t)NTOK * CDIM * 2);
  u16* ub    = (u16*)carve((size_t)NTOK * MLPD * 2);
  u16* wqkvT = (u16*)carve((size_t)LAYERS * QKVD * CDIM * 2);
  u16* woT   = (u16*)carve((size_t)LAYERS * CDIM * CDIM * 2);
  u16* wm1T  = (u16*)carve((size_t)LAYERS * MLPD * CDIM * 2);
  u16* wm2T  = (u16*)carve((size_t)LAYERS * CDIM * MLPD * 2);

  kt_transpose<<<dim3(QKVD/32, CDIM/32, LAYERS), 256, 0, stream>>>(w_qkv, wqkvT, CDIM, QKVD);
  kt_transpose<<<dim3(CDIM/32, CDIM/32, LAYERS), 256, 0, stream>>>(w_o,   woT,   CDIM, CDIM);
  kt_transpose<<<dim3(MLPD/32, CDIM/32, LAYERS), 256, 0, stream>>>(w_m1,  wm1T,  CDIM, MLPD);
  kt_transpose<<<dim3(CDIM/32, MLPD/32, LAYERS), 256, 0, stream>>>(w_m2,  wm2T,  MLPD, CDIM);
  kt_embed<<<NTOK, 256, 0, stream>>>(feats, coords, emb_x, emb_y, emb_z, w_in, b_in, h);

  for (int l = 0; l < LAYERS; ++l){
    kt_ln<<<NTOK/4, 256, 0, stream>>>(h, ln1_g + l*CDIM, ln1_b + l*CDIM, a, 1e-6f);
    kt_gemm<128,128,0><<<(NTOK/128)*(QKVD/128), 256, 0, stream>>>(
        a, wqkvT + (size_t)l*QKVD*CDIM, b_qkv + l*QKVD, qkvb, nullptr, vT, QKVD, CDIM);
    kt_attn<<<512, 256, 0, stream>>>(qkvb, vT, ob);
    kt_gemm<64,64,1><<<(NTOK/64)*(CDIM/64), 256, 0, stream>>>(
        ob, woT + (size_t)l*CDIM*CDIM, b_o + l*CDIM, nullptr, h, nullptr, CDIM, CDIM);
    kt_ln<<<NTOK/4, 256, 0, stream>>>(h, ln2_g + l*CDIM, ln2_b + l*CDIM, a, 1e-6f);
    kt_gemm<128,128,2><<<(NTOK/128)*(MLPD/128), 256, 0, stream>>>(
        a, wm1T + (size_t)l*MLPD*CDIM, b_m1 + l*MLPD, ub, nullptr, nullptr, MLPD, CDIM);
    kt_gemm<64,64,1><<<(NTOK/64)*(CDIM/64), 256, 0, stream>>>(
        ub, wm2T + (size_t)l*CDIM*MLPD, b_m2 + l*CDIM, nullptr, h, nullptr, CDIM, MLPD);
  }
  kt_final<<<NTOK, 64, 0, stream>>>(h, w_out, b_out, coords, offp, (float*)d_out);
}